// Round 27
// baseline (102.030 us; speedup 1.0000x reference)
//
#include <hip/hip_runtime.h>
#include <math.h>

#define HW 262144   // 512*512
#define TAB_SPARSE_OFF 8193
#define FSUM_OFF 32768

__device__ __forceinline__ int clip511f(float t) { return (int)fminf(fmaxf(t, 0.0f), 511.0f); }

// exact f32 MLP logit (table build)
__device__ float mlp_lg(float t,
                        const float* __restrict__ w0, const float* __restrict__ s0,
                        const float* __restrict__ b0, const float* __restrict__ w1,
                        const float* __restrict__ s1, const float* __restrict__ b1,
                        const float* __restrict__ w2, const float* __restrict__ b2) {
    float h0[16];
    #pragma unroll
    for (int k = 0; k < 16; ++k)
        h0[k] = fmaxf((w0[k] * t) * s0[k] + b0[k], 0.0f);
    float lg = b2[0];
    #pragma unroll
    for (int j = 0; j < 8; ++j) {
        float a1 = 0.0f;
        #pragma unroll
        for (int k = 0; k < 16; ++k) a1 += w1[j * 16 + k] * h0[k];
        float h1 = fmaxf(a1 * s1[j] + b1[j], 0.0f);
        lg += w2[j] * h1;
    }
    return lg;
}

__global__ __launch_bounds__(256) void tab_kernel(
    const float* __restrict__ w0, const float* __restrict__ s0, const float* __restrict__ b0,
    const float* __restrict__ w1, const float* __restrict__ s1, const float* __restrict__ b1,
    const float* __restrict__ w2, const float* __restrict__ b2,
    float* __restrict__ ws) {
    int i = blockIdx.x * 256 + threadIdx.x;
    if (i <= 8192) {
        float t = -1024.0f + 0.25f * (float)i;
        ws[i] = mlp_lg(t, w0, s0, b0, w1, s1, b1, w2, b2);
    }
    int j = i - 8448;
    if (j >= 0 && j <= 8192) {
        float t = -131072.0f + 32.0f * (float)j;
        ws[TAB_SPARSE_OFF + j] = mlp_lg(t, w0, s0, b0, w1, s1, b1, w2, b2);
    }
}

__global__ __launch_bounds__(256) void fsum_kernel(const float* __restrict__ rf,
                                                   float* __restrict__ fsum) {
    int t = blockIdx.x * 256 + threadIdx.x;        // 0 .. 131071
    int b = t >> 16;
    int q = t & 65535;
    const float4* src = reinterpret_cast<const float4*>(rf) + (size_t)(b * 32) * 65536 + q;
    float4 acc = make_float4(0.f, 0.f, 0.f, 0.f);
    #pragma unroll
    for (int c = 0; c < 32; ++c) {
        float4 v = src[(size_t)c * 65536];
        acc.x += v.x; acc.y += v.y; acc.z += v.z; acc.w += v.w;
    }
    reinterpret_cast<float4*>(fsum)[t] = acc;
}

// Exact oracle axis chain (tree P=2305)
struct Axis { float wx, om; int c0, c1; };
__device__ __forceinline__ Axis axis_eval(int t_int) {
#pragma clang fp contract(off)
    const float RCP = (float)(1.0 / 255.5);
    float q = (float)t_int * RCP;
    float gp = (q - 1.0f) + 1.0f;
    float ix = ((gp * 512.0f) - 1.0f) * 0.5f;
    float x0 = floorf(ix);
    Axis a;
    a.wx = ix - x0;
    a.om = 1.0f - a.wx;
    a.c0 = clip511f(x0);
    a.c1 = clip511f(x0 + 1.0f);
    return a;
}

// ---------------- patch kernel: one thread = one (x,y), BOTH batches ----------------
__global__ __launch_bounds__(256) void patch_kernel(
    const float* __restrict__ nrm, const float* __restrict__ dv,
    const float* __restrict__ intri, const float* __restrict__ ws,
    const float* __restrict__ w0, const float* __restrict__ s0, const float* __restrict__ b0,
    const float* __restrict__ w1, const float* __restrict__ s1, const float* __restrict__ b1,
    const float* __restrict__ w2, const float* __restrict__ b2,
    float* __restrict__ out)
{
    __shared__ float sW[201];
    int tid = threadIdx.x;
    if (tid < 201) {
        float vv;
        if      (tid < 16)  vv = w0[tid];
        else if (tid < 32)  vv = s0[tid - 16];
        else if (tid < 48)  vv = b0[tid - 32];
        else if (tid < 176) vv = w1[tid - 48];
        else if (tid < 184) vv = s1[tid - 176];
        else if (tid < 192) vv = b1[tid - 184];
        else if (tid < 200) vv = w2[tid - 192];
        else                vv = b2[0];
        sW[tid] = vv;
    }
    __syncthreads();

    int r = blockIdx.x * 256 + tid;   // 0 .. 262143
    int y = r >> 9;
    int x = r & 511;

    // ---- shared (batch-independent) geometry: axes + coordinate samples ----
    float xs_[4], ys_[4];
    int i00t[4], i01t[4], i10t[4], i11t[4];
    float wxt[4], omxt[4], wyt[4], omyt[4];
    {
#pragma clang fp contract(off)
        Axis axm = axis_eval(x - 1);
        Axis ax0 = axis_eval(x);
        Axis axp = axis_eval(x + 1);
        Axis ay0 = axis_eval(y);
        Axis ayp = axis_eval(y + 1);

        // taps (oy,ox): n0=(1,0)->(ax0,ayp), n1=(0,-1)->(axm,ay0),
        //               n2=(0,0)->(ax0,ay0), n3=(0,1)->(axp,ay0)
        const Axis* AX[4] = { &ax0, &axm, &ax0, &axp };
        const Axis* AY[4] = { &ayp, &ay0, &ay0, &ay0 };

        for (int n = 0; n < 4; ++n) {
            const Axis& ax = *AX[n];
            const Axis& ay = *AY[n];
            float wxf = ax.wx, omx = ax.om;
            float wyf = ay.wx, omy = ay.om;
            int x0 = ax.c0, x1 = ax.c1, y0 = ay.c0, y1 = ay.c1;
            wxt[n] = wxf; omxt[n] = omx; wyt[n] = wyf; omyt[n] = omy;
            i00t[n] = y0 * 512 + x0; i01t[n] = y0 * 512 + x1;
            i10t[n] = y1 * 512 + x0; i11t[n] = y1 * 512 + x1;

            // xy coordinate sample — exact flat tree (ε-critical, IEEE)
            float m00 = (float)x0 * omx, m01 = (float)x1 * wxf;
            float m10 = (float)x0 * omx, m11 = (float)x1 * wxf;
            float A = m00 * omy, B = m01 * omy, C = m10 * wyf, D = m11 * wyf;
            xs_[n] = ((A + B) + C) + D;
            float n00 = (float)y0 * omx, n01 = (float)y0 * wxf;
            float n10 = (float)y1 * omx, n11 = (float)y1 * wxf;
            float A2 = n00 * omy, B2 = n01 * omy, C2 = n10 * wyf, D2 = n11 * wyf;
            ys_[n] = ((A2 + B2) + C2) + D2;
        }
    }

    // ---- per-batch ----
    for (int b = 0; b < 2; ++b) {
        float fx = intri[b * 9 + 0], cx = intri[b * 9 + 2];
        float fy = intri[b * 9 + 4], cy = intri[b * 9 + 5];
        const float* nb = nrm + (size_t)(b * 3) * HW;
        const float* fb = ws + FSUM_OFF + (size_t)b * HW;

        float nx = nb[r], ny = nb[HW + r], nz = nb[2 * HW + r];

        float sim[5], F[5], ss, wv[5];
        {
#pragma clang fp contract(off)
            float u[5], v[5];
            float nbn = sqrtf((nx * nx + ny * ny) + nz * nz);

            for (int n = 0; n < 4; ++n) {
                float wxf = wxt[n], omx = omxt[n], wyf = wyt[n], omy = omyt[n];
                int i00 = i00t[n], i01 = i01t[n], i10 = i10t[n], i11 = i11t[n];

                u[n] = (xs_[n] - cx) / fx;
                v[n] = (ys_[n] - cy) / fy;

                float nsx, nsy, nsz;
                {
                    float m00 = nb[i00] * omx, m01 = nb[i01] * wxf;
                    float m10 = nb[i10] * omx, m11 = nb[i11] * wxf;
                    nsx = ((m00 * omy + m01 * omy) + m10 * wyf) + m11 * wyf;
                    float p00 = nb[HW + i00] * omx, p01 = nb[HW + i01] * wxf;
                    float p10 = nb[HW + i10] * omx, p11 = nb[HW + i11] * wxf;
                    nsy = ((p00 * omy + p01 * omy) + p10 * wyf) + p11 * wyf;
                    float q00 = nb[2*HW + i00] * omx, q01 = nb[2*HW + i01] * wxf;
                    float q10 = nb[2*HW + i10] * omx, q11 = nb[2*HW + i11] * wxf;
                    nsz = ((q00 * omy + q01 * omy) + q10 * wyf) + q11 * wyf;
                }

                float dot = (nsx * nx + nsy * ny) + nsz * nz;
                float na  = sqrtf((nsx * nsx + nsy * nsy) + nsz * nsz);
                sim[n] = dot / (fmaxf(na, 1e-8f) * fmaxf(nbn, 1e-8f));   // ε-critical

                float m00 = fb[i00] * omx, m01 = fb[i01] * wxf;
                float m10 = fb[i10] * omx, m11 = fb[i11] * wxf;
                F[n] = ((m00 * omy + m01 * omy) + m10 * wyf) + m11 * wyf;
            }
            u[4] = u[0]; v[4] = v[0]; sim[4] = sim[0]; F[4] = F[0];

            ss = ((sim[0] + sim[1]) + (sim[2] + sim[3])) + sim[4];   // pairwise (ε-critical)

            float num = (nx * u[2] + ny * v[2]) + nz;
            for (int n = 0; n < 5; ++n) {
                float den = (nx * u[n] + ny * v[n]) + nz;   // ε-critical tree
                if (fabsf(den) < 1e-8f) den = (den < 0.0f) ? -1e-8f : 1e-8f;
                float w_ = num * __builtin_amdgcn_rcpf(den);
                if (!isfinite(w_)) w_ = 1.0f;
                wv[n] = w_;
            }
        }

        float rss = __builtin_amdgcn_rcpf(ss);
        float qv[5];
        #pragma unroll
        for (int n = 0; n < 5; ++n) qv[n] = (sim[n] * rss) * F[n];

        size_t dvbase = (size_t)(b * 8) * HW + (size_t)r;
        float dvv[8];
        #pragma unroll
        for (int d = 0; d < 8; ++d) dvv[d] = dv[dvbase + (size_t)d * HW];

        float sv[8];
        #pragma unroll
        for (int dp = 0; dp < 8; ++dp) {
            float acc = 0.0f;
            #pragma unroll
            for (int n = 0; n < 5; ++n) {
                const int flat = n * 8 + dp;
                acc += qv[n] * (wv[flat % 5] * dvv[flat / 5]);
            }
            sv[dp] = acc * 0.03125f;
        }

        // vw via 2-level PWL table (exact MLP for |t| > 2^17)
        float mx = -1e30f;
        #pragma unroll
        for (int d = 0; d < 8; ++d) {
            float t = sv[d];
            float at = fabsf(t);
            float lg;
            if (at < 131072.0f) {
                bool dense = at < 1024.0f;
                const float* g = dense ? ws : (ws + TAB_SPARSE_OFF);
                float T0  = dense ? -1024.0f : -131072.0f;
                float inv = dense ? 4.0f : 0.03125f;
                float p = (t - T0) * inv;
                int idx = (int)p;
                float fr = p - (float)idx;
                float g0 = g[idx], g1 = g[idx + 1];
                lg = g0 + fr * (g1 - g0);
            } else {
                float h0[16];
                #pragma unroll
                for (int k = 0; k < 16; ++k)
                    h0[k] = fmaxf((sW[k] * t) * sW[16 + k] + sW[32 + k], 0.0f);
                lg = sW[200];
                #pragma unroll
                for (int j = 0; j < 8; ++j) {
                    float a1 = 0.0f;
                    #pragma unroll
                    for (int k = 0; k < 16; ++k) a1 += sW[48 + j * 16 + k] * h0[k];
                    float h1 = fmaxf(a1 * sW[176 + j] + sW[184 + j], 0.0f);
                    lg += sW[192 + j] * h1;
                }
            }
            mx = fmaxf(mx, lg);
        }
        float vw = 1.0f / (1.0f + expf(-mx));

        #pragma unroll
        for (int d = 0; d < 8; ++d)
            out[dvbase + (size_t)d * HW] = sv[d] * vw;
    }
}

extern "C" void kernel_launch(void* const* d_in, const int* in_sizes, int n_in,
                              void* d_out, int out_size, void* d_ws, size_t ws_size,
                              hipStream_t stream) {
    const float* rf    = (const float*)d_in[0];
    const float* nrm   = (const float*)d_in[1];
    const float* dv    = (const float*)d_in[2];
    const float* intri = (const float*)d_in[3];
    const float* w0    = (const float*)d_in[4];
    const float* s0    = (const float*)d_in[5];
    const float* b0    = (const float*)d_in[6];
    const float* w1    = (const float*)d_in[7];
    const float* s1    = (const float*)d_in[8];
    const float* b1    = (const float*)d_in[9];
    const float* w2    = (const float*)d_in[10];
    const float* b2    = (const float*)d_in[11];
    float* out = (float*)d_out;
    float* ws  = (float*)d_ws;

    tab_kernel<<<66, 256, 0, stream>>>(w0, s0, b0, w1, s1, b1, w2, b2, ws);
    fsum_kernel<<<512, 256, 0, stream>>>(rf, ws + FSUM_OFF);
    patch_kernel<<<1024, 256, 0, stream>>>(nrm, dv, intri, ws,
                                           w0, s0, b0, w1, s1, b1, w2, b2, out);
}

// Round 28
// 48.058 us; speedup vs baseline: 2.1230x; 2.1230x over previous
//
#include <hip/hip_runtime.h>
#include <math.h>

#define HW 262144   // 512*512
#define TAB_SPARSE_OFF 8193
#define FSUM_OFF 32768

__device__ __forceinline__ int clip511f(float t) { return (int)fminf(fmaxf(t, 0.0f), 511.0f); }

// exact f32 MLP logit (table build)
__device__ float mlp_lg(float t,
                        const float* __restrict__ w0, const float* __restrict__ s0,
                        const float* __restrict__ b0, const float* __restrict__ w1,
                        const float* __restrict__ s1, const float* __restrict__ b1,
                        const float* __restrict__ w2, const float* __restrict__ b2) {
    float h0[16];
    #pragma unroll
    for (int k = 0; k < 16; ++k)
        h0[k] = fmaxf((w0[k] * t) * s0[k] + b0[k], 0.0f);
    float lg = b2[0];
    #pragma unroll
    for (int j = 0; j < 8; ++j) {
        float a1 = 0.0f;
        #pragma unroll
        for (int k = 0; k < 16; ++k) a1 += w1[j * 16 + k] * h0[k];
        float h1 = fmaxf(a1 * s1[j] + b1[j], 0.0f);
        lg += w2[j] * h1;
    }
    return lg;
}

__global__ __launch_bounds__(256) void tab_kernel(
    const float* __restrict__ w0, const float* __restrict__ s0, const float* __restrict__ b0,
    const float* __restrict__ w1, const float* __restrict__ s1, const float* __restrict__ b1,
    const float* __restrict__ w2, const float* __restrict__ b2,
    float* __restrict__ ws) {
    int i = blockIdx.x * 256 + threadIdx.x;
    if (i <= 8192) {
        float t = -1024.0f + 0.25f * (float)i;
        ws[i] = mlp_lg(t, w0, s0, b0, w1, s1, b1, w2, b2);
    }
    int j = i - 8448;
    if (j >= 0 && j <= 8192) {
        float t = -131072.0f + 32.0f * (float)j;
        ws[TAB_SPARSE_OFF + j] = mlp_lg(t, w0, s0, b0, w1, s1, b1, w2, b2);
    }
}

__global__ __launch_bounds__(256) void fsum_kernel(const float* __restrict__ rf,
                                                   float* __restrict__ fsum) {
    int t = blockIdx.x * 256 + threadIdx.x;        // 0 .. 131071
    int b = t >> 16;
    int q = t & 65535;
    const float4* src = reinterpret_cast<const float4*>(rf) + (size_t)(b * 32) * 65536 + q;
    float4 acc = make_float4(0.f, 0.f, 0.f, 0.f);
    #pragma unroll
    for (int c = 0; c < 32; ++c) {
        float4 v = src[(size_t)c * 65536];
        acc.x += v.x; acc.y += v.y; acc.z += v.z; acc.w += v.w;
    }
    reinterpret_cast<float4*>(fsum)[t] = acc;
}

// Exact oracle axis chain (tree P=2305)
struct Axis { float wx, om; int c0, c1; };
__device__ __forceinline__ Axis axis_eval(int t_int) {
#pragma clang fp contract(off)
    const float RCP = (float)(1.0 / 255.5);
    float q = (float)t_int * RCP;
    float gp = (q - 1.0f) + 1.0f;
    float ix = ((gp * 512.0f) - 1.0f) * 0.5f;
    float x0 = floorf(ix);
    Axis a;
    a.wx = ix - x0;
    a.om = 1.0f - a.wx;
    a.c0 = clip511f(x0);
    a.c1 = clip511f(x0 + 1.0f);
    return a;
}

// ---------------- patch kernel: one thread = one (b,x,y); prefetch-all schedule ----------------
__global__ __launch_bounds__(256) void patch_kernel(
    const float* __restrict__ nrm, const float* __restrict__ dv,
    const float* __restrict__ intri, const float* __restrict__ ws,
    const float* __restrict__ w0, const float* __restrict__ s0, const float* __restrict__ b0,
    const float* __restrict__ w1, const float* __restrict__ s1, const float* __restrict__ b1,
    const float* __restrict__ w2, const float* __restrict__ b2,
    float* __restrict__ out)
{
    __shared__ float sW[201];
    int tid = threadIdx.x;
    if (tid < 201) {
        float vv;
        if      (tid < 16)  vv = w0[tid];
        else if (tid < 32)  vv = s0[tid - 16];
        else if (tid < 48)  vv = b0[tid - 32];
        else if (tid < 176) vv = w1[tid - 48];
        else if (tid < 184) vv = s1[tid - 176];
        else if (tid < 192) vv = b1[tid - 184];
        else if (tid < 200) vv = w2[tid - 192];
        else                vv = b2[0];
        sW[tid] = vv;
    }
    __syncthreads();

    int pid = blockIdx.x * 256 + tid;   // 0 .. 524287
    int b = pid >> 18;
    int r = pid & (HW - 1);
    int y = r >> 9;
    int x = r & 511;

    float fx = intri[b * 9 + 0], cx = intri[b * 9 + 2];
    float fy = intri[b * 9 + 4], cy = intri[b * 9 + 5];

    const float* nb = nrm + (size_t)(b * 3) * HW;
    const float* fb = ws + FSUM_OFF + (size_t)b * HW;

    // ---- phase 0: axes + indices (VALU only) ----
    Axis axm = axis_eval(x - 1);
    Axis ax0 = axis_eval(x);
    Axis axp = axis_eval(x + 1);
    Axis ay0 = axis_eval(y);
    Axis ayp = axis_eval(y + 1);

    // taps (oy,ox): n0=(1,0)->(ax0,ayp), n1=(0,-1)->(axm,ay0),
    //               n2=(0,0)->(ax0,ay0), n3=(0,1)->(axp,ay0)
    float wxt[4]  = { ax0.wx, axm.wx, ax0.wx, axp.wx };
    float omxt[4] = { ax0.om, axm.om, ax0.om, axp.om };
    float wyt[4]  = { ayp.wx, ay0.wx, ay0.wx, ay0.wx };
    float omyt[4] = { ayp.om, ay0.om, ay0.om, ay0.om };
    int xc0[4] = { ax0.c0, axm.c0, ax0.c0, axp.c0 };
    int xc1[4] = { ax0.c1, axm.c1, ax0.c1, axp.c1 };
    int yc0[4] = { ayp.c0, ay0.c0, ay0.c0, ay0.c0 };
    int yc1[4] = { ayp.c1, ay0.c1, ay0.c1, ay0.c1 };

    int i00[4], i01[4], i10[4], i11[4];
    #pragma unroll
    for (int n = 0; n < 4; ++n) {
        i00[n] = yc0[n] * 512 + xc0[n]; i01[n] = yc0[n] * 512 + xc1[n];
        i10[n] = yc1[n] * 512 + xc0[n]; i11[n] = yc1[n] * 512 + xc1[n];
    }

    // ---- phase 1: issue ALL loads (64 corners + 3 center normals + 8 dv) ----
    float gx_[4][4], gy_[4][4], gz_[4][4], gF_[4][4];
    #pragma unroll
    for (int n = 0; n < 4; ++n) {
        gx_[n][0] = nb[i00[n]];        gx_[n][1] = nb[i01[n]];
        gx_[n][2] = nb[i10[n]];        gx_[n][3] = nb[i11[n]];
        gy_[n][0] = nb[HW + i00[n]];   gy_[n][1] = nb[HW + i01[n]];
        gy_[n][2] = nb[HW + i10[n]];   gy_[n][3] = nb[HW + i11[n]];
        gz_[n][0] = nb[2*HW + i00[n]]; gz_[n][1] = nb[2*HW + i01[n]];
        gz_[n][2] = nb[2*HW + i10[n]]; gz_[n][3] = nb[2*HW + i11[n]];
        gF_[n][0] = fb[i00[n]];        gF_[n][1] = fb[i01[n]];
        gF_[n][2] = fb[i10[n]];        gF_[n][3] = fb[i11[n]];
    }
    float nx = nb[r], ny = nb[HW + r], nz = nb[2 * HW + r];
    size_t dvbase = (size_t)(b * 8) * HW + (size_t)r;
    float dvv[8];
    #pragma unroll
    for (int d = 0; d < 8; ++d) dvv[d] = dv[dvbase + (size_t)d * HW];

    // ---- phase 2: geometry (ε-critical trees, verbatim) ----
    float sim[5], F[5], ss, wv[5];
    {
#pragma clang fp contract(off)
        float u[5], v[5];
        float nbn = sqrtf((nx * nx + ny * ny) + nz * nz);

        for (int n = 0; n < 4; ++n) {
            float wxf = wxt[n], omx = omxt[n], wyf = wyt[n], omy = omyt[n];
            int x0 = xc0[n], x1 = xc1[n], y0 = yc0[n], y1 = yc1[n];

            // xy coordinate sample — exact flat tree
            {
                float m00 = (float)x0 * omx, m01 = (float)x1 * wxf;
                float m10 = (float)x0 * omx, m11 = (float)x1 * wxf;
                float A = m00 * omy, B = m01 * omy, C = m10 * wyf, D = m11 * wyf;
                float xs_ = ((A + B) + C) + D;
                float n00 = (float)y0 * omx, n01 = (float)y0 * wxf;
                float n10 = (float)y1 * omx, n11 = (float)y1 * wxf;
                float A2 = n00 * omy, B2 = n01 * omy, C2 = n10 * wyf, D2 = n11 * wyf;
                float ys_ = ((A2 + B2) + C2) + D2;
                u[n] = (xs_ - cx) / fx;
                v[n] = (ys_ - cy) / fy;
            }

            // normals bilinear — exact flat tree (values preloaded)
            float nsx, nsy, nsz;
            {
                float m00 = gx_[n][0] * omx, m01 = gx_[n][1] * wxf;
                float m10 = gx_[n][2] * omx, m11 = gx_[n][3] * wxf;
                nsx = ((m00 * omy + m01 * omy) + m10 * wyf) + m11 * wyf;
                float p00 = gy_[n][0] * omx, p01 = gy_[n][1] * wxf;
                float p10 = gy_[n][2] * omx, p11 = gy_[n][3] * wxf;
                nsy = ((p00 * omy + p01 * omy) + p10 * wyf) + p11 * wyf;
                float q00 = gz_[n][0] * omx, q01 = gz_[n][1] * wxf;
                float q10 = gz_[n][2] * omx, q11 = gz_[n][3] * wxf;
                nsz = ((q00 * omy + q01 * omy) + q10 * wyf) + q11 * wyf;
            }

            float dot = (nsx * nx + nsy * ny) + nsz * nz;
            float na  = sqrtf((nsx * nsx + nsy * nsy) + nsz * nsz);
            sim[n] = dot / (fmaxf(na, 1e-8f) * fmaxf(nbn, 1e-8f));   // ε-critical divide

            float m00 = gF_[n][0] * omx, m01 = gF_[n][1] * wxf;
            float m10 = gF_[n][2] * omx, m11 = gF_[n][3] * wxf;
            F[n] = ((m00 * omy + m01 * omy) + m10 * wyf) + m11 * wyf;
        }
        u[4] = u[0]; v[4] = v[0]; sim[4] = sim[0]; F[4] = F[0];

        ss = ((sim[0] + sim[1]) + (sim[2] + sim[3])) + sim[4];   // pairwise (ε-critical)

        float num = (nx * u[2] + ny * v[2]) + nz;
        for (int n = 0; n < 5; ++n) {
            float den = (nx * u[n] + ny * v[n]) + nz;   // ε-critical tree
            if (fabsf(den) < 1e-8f) den = (den < 0.0f) ? -1e-8f : 1e-8f;
            float w_ = num * __builtin_amdgcn_rcpf(den);   // post-cancellation: rcp safe
            if (!isfinite(w_)) w_ = 1.0f;
            wv[n] = w_;
        }
    }

    // smooth contraction (f32, FMA ok)
    float rss = __builtin_amdgcn_rcpf(ss);
    float qv[5];
    #pragma unroll
    for (int n = 0; n < 5; ++n) qv[n] = (sim[n] * rss) * F[n];

    float sv[8];
    #pragma unroll
    for (int dp = 0; dp < 8; ++dp) {
        float acc = 0.0f;
        #pragma unroll
        for (int n = 0; n < 5; ++n) {
            const int flat = n * 8 + dp;
            acc += qv[n] * (wv[flat % 5] * dvv[flat / 5]);
        }
        sv[dp] = acc * 0.03125f;
    }

    // vw via 2-level PWL table (exact MLP for |t| > 2^17)
    float mx = -1e30f;
    #pragma unroll
    for (int d = 0; d < 8; ++d) {
        float t = sv[d];
        float at = fabsf(t);
        float lg;
        if (at < 131072.0f) {
            bool dense = at < 1024.0f;
            const float* g = dense ? ws : (ws + TAB_SPARSE_OFF);
            float T0  = dense ? -1024.0f : -131072.0f;
            float inv = dense ? 4.0f : 0.03125f;
            float p = (t - T0) * inv;
            int idx = (int)p;
            float fr = p - (float)idx;
            float g0 = g[idx], g1 = g[idx + 1];
            lg = g0 + fr * (g1 - g0);
        } else {
            float h0[16];
            #pragma unroll
            for (int k = 0; k < 16; ++k)
                h0[k] = fmaxf((sW[k] * t) * sW[16 + k] + sW[32 + k], 0.0f);
            lg = sW[200];
            #pragma unroll
            for (int j = 0; j < 8; ++j) {
                float a1 = 0.0f;
                #pragma unroll
                for (int k = 0; k < 16; ++k) a1 += sW[48 + j * 16 + k] * h0[k];
                float h1 = fmaxf(a1 * sW[176 + j] + sW[184 + j], 0.0f);
                lg += sW[192 + j] * h1;
            }
        }
        mx = fmaxf(mx, lg);
    }
    float vw = 1.0f / (1.0f + expf(-mx));   // max_d sigmoid == sigmoid(max_d)

    #pragma unroll
    for (int d = 0; d < 8; ++d)
        out[dvbase + (size_t)d * HW] = sv[d] * vw;
}

extern "C" void kernel_launch(void* const* d_in, const int* in_sizes, int n_in,
                              void* d_out, int out_size, void* d_ws, size_t ws_size,
                              hipStream_t stream) {
    const float* rf    = (const float*)d_in[0];
    const float* nrm   = (const float*)d_in[1];
    const float* dv    = (const float*)d_in[2];
    const float* intri = (const float*)d_in[3];
    const float* w0    = (const float*)d_in[4];
    const float* s0    = (const float*)d_in[5];
    const float* b0    = (const float*)d_in[6];
    const float* w1    = (const float*)d_in[7];
    const float* s1    = (const float*)d_in[8];
    const float* b1    = (const float*)d_in[9];
    const float* w2    = (const float*)d_in[10];
    const float* b2    = (const float*)d_in[11];
    float* out = (float*)d_out;
    float* ws  = (float*)d_ws;

    tab_kernel<<<66, 256, 0, stream>>>(w0, s0, b0, w1, s1, b1, w2, b2, ws);
    fsum_kernel<<<512, 256, 0, stream>>>(rf, ws + FSUM_OFF);
    patch_kernel<<<2048, 256, 0, stream>>>(nrm, dv, intri, ws,
                                           w0, s0, b0, w1, s1, b1, w2, b2, out);
}